// Round 3
// baseline (232.113 us; speedup 1.0000x reference)
//
#include <hip/hip_runtime.h>
#include <math.h>

#define T_SEQ 34
#define NTOK 14
#define NE (T_SEQ * NTOK) // 476
#define RPB 64            // rows per block
#define NWAVE 7           // t-chunk waves per block

__global__ __launch_bounds__(448) void micro_fused_kernel(
    const int* __restrict__ idx,
    const float* __restrict__ tok_emb,
    const float* __restrict__ s_amp, const float* __restrict__ s_phase,
    const float* __restrict__ s_slope, const float* __restrict__ s_offset,
    const float* __restrict__ pc_slope, const float* __restrict__ pc_int,
    const float* __restrict__ z_hi, const float* __restrict__ spec,
    const float* __restrict__ q_w, const float* __restrict__ v_w,
    const float* __restrict__ out_A, const float* __restrict__ out_B,
    const float* __restrict__ q_phase,
    const float* __restrict__ ln1_w, const float* __restrict__ ln2_w,
    const float* __restrict__ lnf_w,
    const float* __restrict__ fc1_w, const float* __restrict__ fc1_b,
    const float* __restrict__ fc2_w, const float* __restrict__ fc2_b,
    const float* __restrict__ head_w,
    float* __restrict__ out, int N)
{
    // SoA tables indexed by e = s*14 + tok (conflict-free: lanes share s)
    __shared__ float2 HXY[NE];   // (h2, h3)
    __shared__ float2 HZ0[NE];   // (h4, h0)
    __shared__ float  H1s[NE];   // h1
    __shared__ float  C3x[NE], C3y[NE], C3z[NE]; // q_w^T @ q_rot * invs5 * log2e
    __shared__ float  PosX[T_SEQ], PosY[T_SEQ], PosZ[T_SEQ];
    __shared__ float  TE[NTOK * 2];
    __shared__ float  PMs[10];      // PM[j][c] = sum_i (out_A@out_B)[i][j]*v_w[i][c]
    __shared__ float  Ws[5 * NTOK]; // head_w.T @ tok_emb.T
    __shared__ float  ln2s[5], lnfs[5], fc1ws[10], fc1bs[2], fc2ws[10], fc2bs[5];
    __shared__ int    toksT[T_SEQ * RPB]; // [s][row] transposed

    const int lane  = threadIdx.x;  // row within block
    const int chunk = threadIdx.y;  // t-chunk (one per wave)
    const int tid   = chunk * RPB + lane;

    // ---- per-block table build ----
    {
        const float amp = s_amp[0], ph = s_phase[0], slp = s_slope[0], off = s_offset[0];
        const float pcs = pc_slope[0], pci = pc_int[0];
        const float cph = cosf(q_phase[0]), sph = sinf(q_phase[0]);
        const float escale = 0.44721359549995793f * 1.4426950408889634f; // invsqrt(5)*log2(e)
        for (int e = tid; e < NE; e += 448) {
            int t = e / NTOK, tk = e - t * NTOK;
            float px, py, pz;
            if (t == 33)      { px = 0.f;     py = 0.f;     pz = 0.f; }
            else if (t == 32) { px = z_hi[0]; py = z_hi[1]; pz = z_hi[2]; }
            else if (t == 10) { px = spec[0]; py = spec[1]; pz = spec[2]; }
            else if (t == 21) { px = spec[3]; py = spec[4]; pz = spec[5]; }
            else {
                int i = (t < 10) ? t : (t < 21 ? t - 11 : t - 22);
                float fi = (float)i;
                float ang = 0.62831853071795864769f * fi + ph;
                float mlt = 1.f + pci + pcs * fi;
                px = amp * cosf(ang) * mlt;
                py = amp * sinf(ang) * mlt;
                pz = (slp * fi + off) * mlt;
            }
            if (tk == 0) { PosX[t] = px; PosY[t] = py; PosZ[t] = pz; }
            float x0 = tok_emb[tk * 2], x1 = tok_emb[tk * 2 + 1];
            float ssum = x0*x0 + x1*x1 + px*px + py*py + pz*pz;
            float r = rsqrtf(ssum * 0.2f + 1e-5f);
            float h0 = x0 * r * ln1_w[0], h1 = x1 * r * ln1_w[1];
            float h2 = px * r * ln1_w[2], h3 = py * r * ln1_w[3], h4 = pz * r * ln1_w[4];
            float q0 = q_w[0]  * h2 + q_w[1]  * h3 + q_w[2]  * h4;
            float q1 = q_w[3]  * h2 + q_w[4]  * h3 + q_w[5]  * h4;
            float q2 = q_w[6]  * h2 + q_w[7]  * h3 + q_w[8]  * h4;
            float q3 = q_w[9]  * h2 + q_w[10] * h3 + q_w[11] * h4;
            float q4 = q_w[12] * h2 + q_w[13] * h3 + q_w[14] * h4;
            float r0 = q0 * cph - q1 * sph, r1 = q0 * sph + q1 * cph;
            float r2c = q2 * cph - q3 * sph, r3 = q2 * sph + q3 * cph;
            C3x[e] = (r0*q_w[0] + r1*q_w[3] + r2c*q_w[6] + r3*q_w[9]  + q4*q_w[12]) * escale;
            C3y[e] = (r0*q_w[1] + r1*q_w[4] + r2c*q_w[7] + r3*q_w[10] + q4*q_w[13]) * escale;
            C3z[e] = (r0*q_w[2] + r1*q_w[5] + r2c*q_w[8] + r3*q_w[11] + q4*q_w[14]) * escale;
            HXY[e] = make_float2(h2, h3);
            HZ0[e] = make_float2(h4, h0);
            H1s[e] = h1;
        }
    }
    if (tid < 28) TE[tid] = tok_emb[tid];
    if (tid < 70) {
        int d = tid / NTOK, v = tid - d * NTOK;
        Ws[tid] = head_w[d] * tok_emb[v * 2] + head_w[5 + d] * tok_emb[v * 2 + 1];
    }
    if (tid < 10) {
        int j = tid >> 1, c = tid & 1;
        float acc = 0.f;
        for (int i = 0; i < 5; ++i) {
            float m5 = out_A[i*2] * out_B[j] + out_A[i*2+1] * out_B[5 + j];
            acc += m5 * v_w[i*2 + c];
        }
        PMs[tid] = acc;
    }
    if (tid < 5)  { ln2s[tid] = ln2_w[tid]; lnfs[tid] = lnf_w[tid]; fc2bs[tid] = fc2_b[tid]; }
    if (tid < 10) { fc1ws[tid] = fc1_w[tid]; fc2ws[tid] = fc2_w[tid]; }
    if (tid < 2)  { fc1bs[tid] = fc1_b[tid]; }

    // ---- stage 64 rows of tokens, transposed (coalesced global read) ----
    const int Brows = N / T_SEQ;
    const int rowBase = blockIdx.x * RPB;
    for (int j = tid; j < RPB * T_SEQ; j += 448) {
        int r = j / T_SEQ, s = j - r * T_SEQ;
        int rr = rowBase + r;
        toksT[s * RPB + r] = (rr < Brows) ? idx[rr * T_SEQ + s] : 0;
    }
    __syncthreads();

    const int t_base  = chunk * 5;
    const int loop_end = (chunk == 6) ? 33 : (t_base + 4); // inclusive

    float c3x[5], c3y[5], c3z[5], L[5], A0[5], A1[5];
#pragma unroll
    for (int j = 0; j < 5; ++j) {
        L[j] = 0.f; A0[j] = 0.f; A1[j] = 0.f;
        int t = t_base + j;
        if (t < T_SEQ) {
            int e = t * NTOK + toksT[t * RPB + lane];
            c3x[j] = C3x[e]; c3y[j] = C3y[e]; c3z[j] = C3z[e];
        } else { c3x[j] = 0.f; c3y[j] = 0.f; c3z[j] = 0.f; }
    }

    // ---- loop 1: s < t_base — all 5 t's active, no guards ----
    for (int s = 0; s < t_base; ++s) {
        int e = s * NTOK + toksT[s * RPB + lane];
        float2 hxy = HXY[e], hz0 = HZ0[e];
        float h1 = H1s[e];
#pragma unroll
        for (int j = 0; j < 5; ++j) {
            float sc = fmaf(c3x[j], hxy.x, fmaf(c3y[j], hxy.y, c3z[j] * hz0.x));
            float p = exp2f(sc);
            L[j] += p;
            A0[j] = fmaf(p, hz0.y, A0[j]);
            A1[j] = fmaf(p, h1, A1[j]);
        }
    }
    // ---- loop 2: diagonal tail, wave-uniform guards ----
    for (int s = t_base; s <= loop_end; ++s) {
        int e = s * NTOK + toksT[s * RPB + lane];
        float2 hxy = HXY[e], hz0 = HZ0[e];
        float h1 = H1s[e];
#pragma unroll
        for (int j = 0; j < 5; ++j) {
            if (s <= t_base + j) {
                float sc = fmaf(c3x[j], hxy.x, fmaf(c3y[j], hxy.y, c3z[j] * hz0.x));
                float p = exp2f(sc);
                L[j] += p;
                A0[j] = fmaf(p, hz0.y, A0[j]);
                A1[j] = fmaf(p, h1, A1[j]);
            }
        }
    }

    // ---- epilogue: one output row-element per (lane, t) ----
    const int r = rowBase + lane;
    if (r >= Brows) return;
#pragma unroll
    for (int j = 0; j < 5; ++j) {
        int t = t_base + j;
        if (t < T_SEQ) {
            float il = 1.f / L[j];
            float a0 = A0[j] * il, a1 = A1[j] * il;
            int tok = toksT[t * RPB + lane];
            float xv0 = TE[tok * 2], xv1 = TE[tok * 2 + 1];
            float xv2 = PosX[t], xv3 = PosY[t], xv4 = PosZ[t];
            float y[5];
            y[0] = xv0 + PMs[0] * a0 + PMs[1] * a1;
            y[1] = xv1 + PMs[2] * a0 + PMs[3] * a1;
            y[2] = xv2 + PMs[4] * a0 + PMs[5] * a1;
            y[3] = xv3 + PMs[6] * a0 + PMs[7] * a1;
            y[4] = xv4 + PMs[8] * a0 + PMs[9] * a1;

            float s2 = y[0]*y[0] + y[1]*y[1] + y[2]*y[2] + y[3]*y[3] + y[4]*y[4];
            float r2 = rsqrtf(s2 * 0.2f + 1e-5f);
            float hh[5];
#pragma unroll
            for (int k = 0; k < 5; ++k) hh[k] = y[k] * r2 * ln2s[k];

            float u0 = fc1bs[0], u1 = fc1bs[1];
#pragma unroll
            for (int k = 0; k < 5; ++k) { u0 += hh[k] * fc1ws[k]; u1 += hh[k] * fc1ws[5 + k]; }
            float g0 = 0.5f * u0 * (1.f + erff(u0 * 0.70710678118654752f));
            float g1 = 0.5f * u1 * (1.f + erff(u1 * 0.70710678118654752f));

            float y2[5]; float s3 = 0.f;
#pragma unroll
            for (int k = 0; k < 5; ++k) {
                y2[k] = y[k] + g0 * fc2ws[k * 2] + g1 * fc2ws[k * 2 + 1] + fc2bs[k];
                s3 += y2[k] * y2[k];
            }
            float r3 = rsqrtf(s3 * 0.2f + 1e-5f);
            float z[5];
#pragma unroll
            for (int k = 0; k < 5; ++k) z[k] = y2[k] * r3 * lnfs[k];

            float res[14];
#pragma unroll
            for (int v = 0; v < 14; ++v)
                res[v] = z[0] * Ws[v] + z[1] * Ws[14 + v] + z[2] * Ws[28 + v]
                       + z[3] * Ws[42 + v] + z[4] * Ws[56 + v];

            float2* op = (float2*)(out + (size_t)(r * T_SEQ + t) * 14);
#pragma unroll
            for (int v = 0; v < 7; ++v) op[v] = make_float2(res[2 * v], res[2 * v + 1]);
        }
    }
}

extern "C" void kernel_launch(void* const* d_in, const int* in_sizes, int n_in,
                              void* d_out, int out_size, void* d_ws, size_t ws_size,
                              hipStream_t stream) {
    const int N = in_sizes[0]; // B*T
    const int Brows = N / T_SEQ;
    dim3 block(RPB, NWAVE);
    dim3 grid((Brows + RPB - 1) / RPB);
    micro_fused_kernel<<<grid, block, 0, stream>>>(
        (const int*)d_in[0],
        (const float*)d_in[1], (const float*)d_in[2], (const float*)d_in[3],
        (const float*)d_in[4], (const float*)d_in[5], (const float*)d_in[6],
        (const float*)d_in[7], (const float*)d_in[8], (const float*)d_in[9],
        (const float*)d_in[10], (const float*)d_in[11], (const float*)d_in[12],
        (const float*)d_in[13], (const float*)d_in[14], (const float*)d_in[15],
        (const float*)d_in[16], (const float*)d_in[17], (const float*)d_in[18],
        (const float*)d_in[19], (const float*)d_in[20], (const float*)d_in[21],
        (const float*)d_in[22],
        (float*)d_out, N);
}